// Round 3
// baseline (600.224 us; speedup 1.0000x reference)
//
#include <hip/hip_runtime.h>
#include <stdint.h>

#define D 128
#define RNUM 4
#define TM 32          // nodes per GEMM tile / bucket

typedef unsigned short u16;
typedef __attribute__((ext_vector_type(8))) short short8;
typedef __attribute__((ext_vector_type(4))) float floatx4;

__device__ inline u16 f2bf(float f) {
  union { float f; uint32_t u; } c; c.f = f;
  uint32_t r = (c.u + 0x7FFFu + ((c.u >> 16) & 1u)) >> 16;
  return (u16)r;
}
__device__ inline uint32_t pack2(float a, float b) {
  return (uint32_t)f2bf(a) | ((uint32_t)f2bf(b) << 16);
}

__device__ inline float fast_tanh(float v) {
  float a = fabsf(v);
  float e = __builtin_amdgcn_exp2f(a * 2.8853900817779268f);  // e^(2a)
  float t = 1.0f - 2.0f * __builtin_amdgcn_rcpf(e + 1.0f);
  return copysignf(t, v);
}

// Build Wt[r][col][k] (bf16; k<128 -> W_rel[r][k][col], else W_root[r][k-128][col]) and bias.
__global__ void prep_kernel(const float* __restrict__ W_rel, const float* __restrict__ b_rel,
                            const float* __restrict__ W_root, const float* __restrict__ b_root,
                            u16* __restrict__ Wt, float* __restrict__ bias) {
  int idx = blockIdx.x * 256 + threadIdx.x;
  if (idx < RNUM * D) bias[idx] = b_rel[idx] + b_root[idx];
  if (idx >= RNUM * D * 2 * D) return;
  int k   = idx & 255;
  int col = (idx >> 8) & 127;
  int r   = idx >> 15;
  float v = (k < D) ? W_rel[((size_t)r * D + k) * D + col]
                    : W_root[((size_t)r * D + (k - D)) * D + col];
  Wt[idx] = f2bf(v);
}

// counts[(dst>>5)*4 + rel]++
__global__ void hist_kernel(const int* __restrict__ ei, const int* __restrict__ ea,
                            uint32_t* __restrict__ counts, int E) {
  int t = blockIdx.x * 256 + threadIdx.x;
  if (t >= E) return;
  int dst = ei[E + t];
  int rel = ea[t];
  atomicAdd(&counts[(dst >> 5) * 4 + rel], 1u);
}

// Single-block exclusive scan over n (<=16384) counts -> offsets[0..n], cursor copy.
__global__ __launch_bounds__(1024) void scan_kernel(const uint32_t* __restrict__ counts,
                                                    uint32_t* __restrict__ offsets,
                                                    uint32_t* __restrict__ cursor, int n) {
  __shared__ uint32_t sums[1024];
  int t = threadIdx.x;
  uint32_t loc[16];
  uint32_t s = 0;
#pragma unroll
  for (int i = 0; i < 16; ++i) {
    int idx = t * 16 + i;
    uint32_t c = (idx < n) ? counts[idx] : 0u;
    loc[i] = s;
    s += c;
  }
  sums[t] = s;
  __syncthreads();
  for (int off = 1; off < 1024; off <<= 1) {
    uint32_t v = (t >= off) ? sums[t - off] : 0u;
    __syncthreads();
    sums[t] += v;
    __syncthreads();
  }
  uint32_t base = (t == 0) ? 0u : sums[t - 1];
#pragma unroll
  for (int i = 0; i < 16; ++i) {
    int idx = t * 16 + i;
    if (idx < n) {
      uint32_t v = base + loc[i];
      offsets[idx] = v;
      cursor[idx] = v;
    }
  }
  if (t == 1023) offsets[n] = sums[1023];
}

// recs[pos] = src | (local<<17), bucketed by ((dst>>5)*4 + rel)
__global__ void fill_kernel(const int* __restrict__ ei, const int* __restrict__ ea,
                            uint32_t* __restrict__ cursor, uint32_t* __restrict__ recs, int E) {
  int t = blockIdx.x * 256 + threadIdx.x;
  if (t >= E) return;
  int src = ei[t];
  int dst = ei[E + t];
  int rel = ea[t];
  uint32_t pos = atomicAdd(&cursor[(dst >> 5) * 4 + rel], 1u);
  recs[pos] = (uint32_t)src | ((uint32_t)(dst & 31) << 17);
}

// Fused gather-aggregate (fp32 LDS, dim-interleaved) -> bf16 convert -> MFMA GEMM + tanh.
// 512 threads = 8 waves. Waves w and w+4 split relation-(w&3)'s segment.
// MFMA: wave w owns output cols [w*16, w*16+16).
// fp32 accumulator layout within a slot: dim d at offset (d&1)*64 + (d>>1)  (2-way bank only).
__global__ __launch_bounds__(512, 4) void fused_kernel(
    const float* __restrict__ x, const uint32_t* __restrict__ recs,
    const uint32_t* __restrict__ offsets,
    const u16* __restrict__ Wt, const float* __restrict__ bias,
    float* __restrict__ out, int N) {
  __shared__ __align__(16) float aggF[4 * TM * D];   // 64 KB; bf16 slots overlay front 32 KB
  __shared__ __align__(16) u16 sX[TM * D];           // 8 KB  (x slot, swizzled bf16)

  const int tid = threadIdx.x;
  const int w = tid >> 6, l = tid & 63;
  const int nodeBase = blockIdx.x * TM;

  // ---- zero aggF: 4096 float4 / 512 threads ----
  float4 z = {0.f, 0.f, 0.f, 0.f};
#pragma unroll
  for (int i = 0; i < 8; ++i) ((float4*)aggF)[tid + i * 512] = z;

  // ---- stage x slot: swizzled bf16, 512 chunks, 1/thread ----
  {
    int c = tid & 15, node = tid >> 4;
    int gnode = nodeBase + node;
    uint4 pk = {0u, 0u, 0u, 0u};
    if (gnode < N) {
      const float* s = x + (size_t)gnode * D + c * 8;
      float4 lo = *(const float4*)s;
      float4 hi = *(const float4*)(s + 4);
      pk.x = pack2(lo.x, lo.y); pk.y = pack2(lo.z, lo.w);
      pk.z = pack2(hi.x, hi.y); pk.w = pack2(hi.z, hi.w);
    }
    *(uint4*)&sX[node * D + ((c ^ (node & 7)) << 3)] = pk;
  }
  __syncthreads();

  // ---- phase A: gather + LDS accumulate; lane l handles dims 2l, 2l+1 ----
  {
    int seg = blockIdx.x * 4 + (w & 3);
    int half = w >> 2;
    uint32_t i0 = (uint32_t)__builtin_amdgcn_readfirstlane((int)offsets[seg]);
    uint32_t i1 = (uint32_t)__builtin_amdgcn_readfirstlane((int)offsets[seg + 1]);
    uint32_t h = ((i1 - i0) + 1) >> 1;
    uint32_t b0 = i0 + (uint32_t)half * h;
    uint32_t b1 = half ? i1 : (i0 + h);
    float* aw = aggF + (w & 3) * (TM * D);
    uint32_t i = b0;
    for (; i + 8 <= b1; i += 8) {
      uint32_t rc[8];
#pragma unroll
      for (int j = 0; j < 8; ++j) rc[j] = recs[i + j];
      float2 v[8];
#pragma unroll
      for (int j = 0; j < 8; ++j)
        v[j] = *(const float2*)(x + (size_t)(rc[j] & 0x1FFFF) * D + 2 * l);
#pragma unroll
      for (int j = 0; j < 8; ++j) {
        int node = (int)((rc[j] >> 17) & 31);
        atomicAdd(&aw[node * D + l], v[j].x);         // dim 2l   -> offset l
        atomicAdd(&aw[node * D + 64 + l], v[j].y);    // dim 2l+1 -> offset 64+l
      }
    }
    for (; i < b1; ++i) {
      uint32_t rc0 = recs[i];
      float2 v0 = *(const float2*)(x + (size_t)(rc0 & 0x1FFFF) * D + 2 * l);
      int node = (int)((rc0 >> 17) & 31);
      atomicAdd(&aw[node * D + l], v0.x);
      atomicAdd(&aw[node * D + 64 + l], v0.y);
    }
  }
  __syncthreads();

  // ---- convert agg slots f32 (interleaved dims) -> swizzled bf16, in place ----
  // chunk c (dims 8c..8c+7): evens = float4 at offset 4c, odds = float4 at 64+4c.
  {
    int c = tid & 15, node = tid >> 4;
#pragma unroll
    for (int s = 0; s < 4; ++s) {
      const float* slotF = aggF + s * (TM * D) + node * D;
      float4 ev = ((const float4*)slotF)[c];
      float4 od = ((const float4*)(slotF + 64))[c];
      __syncthreads();
      uint4 pk;
      pk.x = pack2(ev.x, od.x);
      pk.y = pack2(ev.y, od.y);
      pk.z = pack2(ev.z, od.z);
      pk.w = pack2(ev.w, od.w);
      *(uint4*)((u16*)aggF + s * (TM * D) + node * D + ((c ^ (node & 7)) << 3)) = pk;
      __syncthreads();
    }
  }

  // ---- MFMA phase: wave w -> cols [w*16, w*16+16) ----
  const int lrow = l & 15, lhi = l >> 4;
  floatx4 oacc[2];
  oacc[0] = (floatx4){0.f, 0.f, 0.f, 0.f};
  oacc[1] = (floatx4){0.f, 0.f, 0.f, 0.f};

  for (int r = 0; r < RNUM; ++r) {
    floatx4 acc[2];
    acc[0] = (floatx4){0.f, 0.f, 0.f, 0.f};
    acc[1] = (floatx4){0.f, 0.f, 0.f, 0.f};

#pragma unroll
    for (int ks = 0; ks < 8; ++ks) {
      const u16* Abase = (ks < 4) ? ((const u16*)aggF + r * (TM * D)) : sX;
      const int cRead = (ks & 3) * 4 + lhi;
      short8 afr[2];
#pragma unroll
      for (int m = 0; m < 2; ++m) {
        int node = m * 16 + lrow;
        afr[m] = *(const short8*)&Abase[node * D + ((cRead ^ (node & 7)) << 3)];
      }
      int col = w * 16 + lrow;
      short8 bfr = *(const short8*)(Wt + ((size_t)(r * D + col) * (2 * D) + ks * 32 + lhi * 8));
#pragma unroll
      for (int m = 0; m < 2; ++m)
        acc[m] = __builtin_amdgcn_mfma_f32_16x16x32_bf16(afr[m], bfr, acc[m], 0, 0, 0);
    }

    float bb = bias[r * D + w * 16 + lrow];
#pragma unroll
    for (int m = 0; m < 2; ++m)
#pragma unroll
      for (int j = 0; j < 4; ++j)
        oacc[m][j] += fast_tanh(acc[m][j] + bb);
  }

  // ---- store: C row = lhi*4 + j, col = lane&15 ----
#pragma unroll
  for (int m = 0; m < 2; ++m) {
#pragma unroll
    for (int j = 0; j < 4; ++j) {
      int node = nodeBase + m * 16 + lhi * 4 + j;
      if (node < N) out[(size_t)node * D + w * 16 + lrow] = oacc[m][j];
    }
  }
}

extern "C" void kernel_launch(void* const* d_in, const int* in_sizes, int n_in,
                              void* d_out, int out_size, void* d_ws, size_t ws_size,
                              hipStream_t stream) {
  const float* x      = (const float*)d_in[0];
  const int*   ei     = (const int*)d_in[1];
  const int*   ea     = (const int*)d_in[2];
  const float* W_rel  = (const float*)d_in[3];
  const float* b_rel  = (const float*)d_in[4];
  const float* W_root = (const float*)d_in[5];
  const float* b_root = (const float*)d_in[6];
  float* out = (float*)d_out;

  const int N = in_sizes[0] / D;   // 100000
  const int E = in_sizes[2];       // 640000
  const int NB = (N + TM - 1) / TM;       // 3125 buckets
  const int NSEG = NB * RNUM;             // 12500 segments

  // ws layout
  u16*      Wt      = (u16*)d_ws;                                  // 256 KB
  float*    bias    = (float*)((char*)d_ws + 262144);              // 2 KB
  uint32_t* counts  = (uint32_t*)((char*)d_ws + 264192);           // 50 KB
  uint32_t* offsets = (uint32_t*)((char*)d_ws + 314368);           // 50 KB
  uint32_t* cursor  = (uint32_t*)((char*)d_ws + 364544);           // 50 KB
  uint32_t* recs    = (uint32_t*)((char*)d_ws + 414720);           // 2.56 MB

  prep_kernel<<<(RNUM * D * 2 * D + 255) / 256, 256, 0, stream>>>(W_rel, b_rel, W_root, b_root, Wt, bias);
  (void)hipMemsetAsync(counts, 0, (size_t)NSEG * 4, stream);
  hist_kernel<<<(E + 255) / 256, 256, 0, stream>>>(ei, ea, counts, E);
  scan_kernel<<<1, 1024, 0, stream>>>(counts, offsets, cursor, NSEG);
  fill_kernel<<<(E + 255) / 256, 256, 0, stream>>>(ei, ea, cursor, recs, E);
  fused_kernel<<<NB, 512, 0, stream>>>(x, recs, offsets, Wt, bias, out, N);
}

// Round 4
// 234.294 us; speedup vs baseline: 2.5618x; 2.5618x over previous
//
#include <hip/hip_runtime.h>
#include <stdint.h>

#define D 128
#define RNUM 4
#define TM 32          // nodes per GEMM tile

typedef unsigned short u16;
typedef __attribute__((ext_vector_type(8))) short short8;
typedef __attribute__((ext_vector_type(4))) float floatx4;

__device__ inline u16 f2bf(float f) {
  union { float f; uint32_t u; } c; c.f = f;
  uint32_t r = (c.u + 0x7FFFu + ((c.u >> 16) & 1u)) >> 16;
  return (u16)r;
}
__device__ inline uint32_t pack2(float a, float b) {
  return (uint32_t)f2bf(a) | ((uint32_t)f2bf(b) << 16);
}

__device__ inline float fast_tanh(float v) {
  float a = fabsf(v);
  float e = __builtin_amdgcn_exp2f(a * 2.8853900817779268f);  // e^(2a)
  float t = 1.0f - 2.0f * __builtin_amdgcn_rcpf(e + 1.0f);
  return copysignf(t, v);
}

// Build Wt[r][col][k] (bf16; k<128 -> W_rel[r][k][col], else W_root[r][k-128][col]) and bias.
__global__ void prep_kernel(const float* __restrict__ W_rel, const float* __restrict__ b_rel,
                            const float* __restrict__ W_root, const float* __restrict__ b_root,
                            u16* __restrict__ Wt, float* __restrict__ bias) {
  int idx = blockIdx.x * 256 + threadIdx.x;
  if (idx < RNUM * D) bias[idx] = b_rel[idx] + b_root[idx];
  if (idx >= RNUM * D * 2 * D) return;
  int k   = idx & 255;
  int col = (idx >> 8) & 127;
  int r   = idx >> 15;
  float v = (k < D) ? W_rel[((size_t)r * D + k) * D + col]
                    : W_root[((size_t)r * D + (k - D)) * D + col];
  Wt[idx] = f2bf(v);
}

// counts[dst*4 + rel]++  (one counter per (node, relation))
__global__ void hist_kernel(const int* __restrict__ ei, const int* __restrict__ ea,
                            uint32_t* __restrict__ counts, int E) {
  int t = blockIdx.x * 256 + threadIdx.x;
  if (t >= E) return;
  atomicAdd(&counts[ei[E + t] * 4 + ea[t]], 1u);
}

// Hierarchical exclusive scan over n = N*4 counters.
__global__ __launch_bounds__(1024) void scan1_kernel(const uint32_t* __restrict__ counts,
                                                     uint32_t* __restrict__ offsets,
                                                     uint32_t* __restrict__ bsums, int n) {
  __shared__ uint32_t s[1024];
  int t = threadIdx.x;
  int g = blockIdx.x * 1024 + t;
  uint32_t c = (g < n) ? counts[g] : 0u;
  s[t] = c;
  __syncthreads();
  for (int off = 1; off < 1024; off <<= 1) {
    uint32_t v = (t >= off) ? s[t - off] : 0u;
    __syncthreads();
    s[t] += v;
    __syncthreads();
  }
  if (g < n) offsets[g] = s[t] - c;           // block-local exclusive
  if (t == 1023) bsums[blockIdx.x] = s[1023]; // block total
}

__global__ __launch_bounds__(512) void scan2_kernel(uint32_t* __restrict__ bsums, int nb) {
  __shared__ uint32_t s[512];
  int t = threadIdx.x;
  uint32_t c = (t < nb) ? bsums[t] : 0u;
  s[t] = c;
  __syncthreads();
  for (int off = 1; off < 512; off <<= 1) {
    uint32_t v = (t >= off) ? s[t - off] : 0u;
    __syncthreads();
    s[t] += v;
    __syncthreads();
  }
  if (t < nb) bsums[t] = s[t] - c;            // exclusive block prefix
}

__global__ __launch_bounds__(1024) void scan3_kernel(uint32_t* __restrict__ offsets,
                                                     uint32_t* __restrict__ cursor,
                                                     const uint32_t* __restrict__ bsums,
                                                     int n, int total) {
  int g = blockIdx.x * 1024 + threadIdx.x;
  if (g < n) {
    uint32_t v = offsets[g] + bsums[blockIdx.x];
    offsets[g] = v;
    cursor[g] = v;
  }
  if (g == 0) offsets[n] = (uint32_t)total;
}

// recs[pos] = src, bucketed by (dst*4 + rel)
__global__ void fill_kernel(const int* __restrict__ ei, const int* __restrict__ ea,
                            uint32_t* __restrict__ cursor, uint32_t* __restrict__ recs, int E) {
  int t = blockIdx.x * 256 + threadIdx.x;
  if (t >= E) return;
  uint32_t pos = atomicAdd(&cursor[ei[E + t] * 4 + ea[t]], 1u);
  recs[pos] = (uint32_t)ei[t];
}

// Fused gather (register accumulate, NO LDS atomics) -> bf16 swizzled LDS -> MFMA GEMM + tanh.
// 512 threads = 8 waves. Wave w owns 16 contiguous (node,rel) rows: rows w*16+t,
// t=0..15 -> node = w*4 + (t>>2), rel = t&3. Lane l accumulates dims (2l, 2l+1).
// LDS: sA slots 0..3 = per-relation agg (bf16, chunk-XOR swizzled), slot 4 = x.
__global__ __launch_bounds__(512, 8) void fused_kernel(
    const float* __restrict__ x, const uint32_t* __restrict__ recs,
    const uint32_t* __restrict__ offsets,
    const u16* __restrict__ Wt, const float* __restrict__ bias,
    float* __restrict__ out, int N) {
  __shared__ __align__(16) u16 sA[5 * TM * D];   // 40 KB

  const int tid = threadIdx.x;
  const int w = tid >> 6, l = tid & 63;
  const int nodeBase = blockIdx.x * TM;

  // ---- stage x slot: swizzled bf16, 512 chunks, 1/thread ----
  {
    int c = tid & 15, node = tid >> 4;
    int gnode = nodeBase + node;
    uint4 pk = {0u, 0u, 0u, 0u};
    if (gnode < N) {
      const float* s = x + (size_t)gnode * D + c * 8;
      float4 lo = *(const float4*)s;
      float4 hi = *(const float4*)(s + 4);
      pk.x = pack2(lo.x, lo.y); pk.y = pack2(lo.z, lo.w);
      pk.z = pack2(hi.x, hi.y); pk.w = pack2(hi.z, hi.w);
    }
    *(uint4*)&sA[4 * (TM * D) + node * D + ((c ^ (node & 7)) << 3)] = pk;
  }

  // ---- gather: wave walks its contiguous edge range, register accumulate, flush per row ----
  {
    const uint32_t* op = offsets + ((size_t)blockIdx.x * (TM * 4) + w * 16);
    uint32_t e  = (uint32_t)__builtin_amdgcn_readfirstlane((int)op[0]);
    uint32_t eE = (uint32_t)__builtin_amdgcn_readfirstlane((int)op[16]);
    int tr = 0;
    uint32_t bnd = (uint32_t)__builtin_amdgcn_readfirstlane((int)op[1]);
    float ax = 0.f, ay = 0.f;
    const int ch = l >> 2, q2 = (l & 3) * 2;

#define FLUSH_ROW do {                                                         \
      int node_ = w * 4 + (tr >> 2); int rel_ = tr & 3;                        \
      int idx_ = rel_ * (TM * D) + node_ * D + ((ch ^ (node_ & 7)) << 3) + q2; \
      *(uint32_t*)&sA[idx_] = pack2(ax, ay);                                   \
      ax = 0.f; ay = 0.f; ++tr;                                                \
      bnd = (tr < 16) ? (uint32_t)__builtin_amdgcn_readfirstlane((int)op[tr + 1]) \
                      : 0xFFFFFFFFu;                                           \
    } while (0)

    for (; e + 4 <= eE; e += 4) {
      uint32_t s0 = recs[e], s1 = recs[e + 1], s2 = recs[e + 2], s3 = recs[e + 3];
      float2 v0 = *(const float2*)(x + (size_t)s0 * D + 2 * l);
      float2 v1 = *(const float2*)(x + (size_t)s1 * D + 2 * l);
      float2 v2 = *(const float2*)(x + (size_t)s2 * D + 2 * l);
      float2 v3 = *(const float2*)(x + (size_t)s3 * D + 2 * l);
      while (e >= bnd) FLUSH_ROW;
      ax += v0.x; ay += v0.y;
      while (e + 1 >= bnd) FLUSH_ROW;
      ax += v1.x; ay += v1.y;
      while (e + 2 >= bnd) FLUSH_ROW;
      ax += v2.x; ay += v2.y;
      while (e + 3 >= bnd) FLUSH_ROW;
      ax += v3.x; ay += v3.y;
    }
    for (; e < eE; ++e) {
      while (e >= bnd) FLUSH_ROW;
      uint32_t s0 = recs[e];
      float2 v0 = *(const float2*)(x + (size_t)s0 * D + 2 * l);
      ax += v0.x; ay += v0.y;
    }
    while (tr < 16) FLUSH_ROW;
#undef FLUSH_ROW
  }
  __syncthreads();

  // ---- MFMA phase: wave w -> cols [w*16, w*16+16) ----
  const int lrow = l & 15, lhi = l >> 4;
  floatx4 oacc[2];
  oacc[0] = (floatx4){0.f, 0.f, 0.f, 0.f};
  oacc[1] = (floatx4){0.f, 0.f, 0.f, 0.f};

  for (int r = 0; r < RNUM; ++r) {
    floatx4 acc[2];
    acc[0] = (floatx4){0.f, 0.f, 0.f, 0.f};
    acc[1] = (floatx4){0.f, 0.f, 0.f, 0.f};

#pragma unroll
    for (int ks = 0; ks < 8; ++ks) {
      const u16* Abase = (ks < 4) ? (sA + r * (TM * D)) : (sA + 4 * (TM * D));
      const int cRead = (ks & 3) * 4 + lhi;
      short8 afr[2];
#pragma unroll
      for (int m = 0; m < 2; ++m) {
        int node = m * 16 + lrow;
        afr[m] = *(const short8*)&Abase[node * D + ((cRead ^ (node & 7)) << 3)];
      }
      int col = w * 16 + lrow;
      short8 bfr = *(const short8*)(Wt + ((size_t)(r * D + col) * (2 * D) + ks * 32 + lhi * 8));
#pragma unroll
      for (int m = 0; m < 2; ++m)
        acc[m] = __builtin_amdgcn_mfma_f32_16x16x32_bf16(afr[m], bfr, acc[m], 0, 0, 0);
    }

    float bb = bias[r * D + w * 16 + lrow];
#pragma unroll
    for (int m = 0; m < 2; ++m)
#pragma unroll
      for (int j = 0; j < 4; ++j)
        oacc[m][j] += fast_tanh(acc[m][j] + bb);
  }

  // ---- store: C row = lhi*4 + j, col = lane&15 ----
#pragma unroll
  for (int m = 0; m < 2; ++m) {
#pragma unroll
    for (int j = 0; j < 4; ++j) {
      int node = nodeBase + m * 16 + lhi * 4 + j;
      if (node < N) out[(size_t)node * D + w * 16 + lrow] = oacc[m][j];
    }
  }
}

extern "C" void kernel_launch(void* const* d_in, const int* in_sizes, int n_in,
                              void* d_out, int out_size, void* d_ws, size_t ws_size,
                              hipStream_t stream) {
  const float* x      = (const float*)d_in[0];
  const int*   ei     = (const int*)d_in[1];
  const int*   ea     = (const int*)d_in[2];
  const float* W_rel  = (const float*)d_in[3];
  const float* b_rel  = (const float*)d_in[4];
  const float* W_root = (const float*)d_in[5];
  const float* b_root = (const float*)d_in[6];
  float* out = (float*)d_out;

  const int N = in_sizes[0] / D;          // 100000
  const int E = in_sizes[2];              // 640000
  const int NB = (N + TM - 1) / TM;       // 3125 tiles
  const int NSEG = N * RNUM;              // 400000 (node, rel) segments
  const int NBLK = (NSEG + 1023) / 1024;  // 391

  // ws layout (256B-aligned regions)
  size_t o = 0;
  auto nxt = [&](size_t bytes) { size_t p = o; o += (bytes + 255) & ~(size_t)255; return p; };
  u16*      Wt      = (u16*)((char*)d_ws + nxt((size_t)RNUM * D * 2 * D * 2));
  float*    bias    = (float*)((char*)d_ws + nxt((size_t)RNUM * D * 4));
  uint32_t* counts  = (uint32_t*)((char*)d_ws + nxt((size_t)NSEG * 4));
  uint32_t* offsets = (uint32_t*)((char*)d_ws + nxt((size_t)(NSEG + 1) * 4));
  uint32_t* cursor  = (uint32_t*)((char*)d_ws + nxt((size_t)NSEG * 4));
  uint32_t* bsums   = (uint32_t*)((char*)d_ws + nxt((size_t)NBLK * 4));
  uint32_t* recs    = (uint32_t*)((char*)d_ws + nxt((size_t)E * 4));

  prep_kernel<<<(RNUM * D * 2 * D + 255) / 256, 256, 0, stream>>>(W_rel, b_rel, W_root, b_root, Wt, bias);
  (void)hipMemsetAsync(counts, 0, (size_t)NSEG * 4, stream);
  hist_kernel<<<(E + 255) / 256, 256, 0, stream>>>(ei, ea, counts, E);
  scan1_kernel<<<NBLK, 1024, 0, stream>>>(counts, offsets, bsums, NSEG);
  scan2_kernel<<<1, 512, 0, stream>>>(bsums, NBLK);
  scan3_kernel<<<NBLK, 1024, 0, stream>>>(offsets, cursor, bsums, NSEG, E);
  fill_kernel<<<(E + 255) / 256, 256, 0, stream>>>(ei, ea, cursor, recs, E);
  fused_kernel<<<NB, 512, 0, stream>>>(x, recs, offsets, Wt, bias, out, N);
}